// Round 9
// baseline (1223.950 us; speedup 1.0000x reference)
//
#include <hip/hip_runtime.h>
#include <hip/hip_bf16.h>
#include <math.h>

// Problem constants
#define BB 4
#define TT 2048
#define BT 8192          // B*T rows
#define DM 512           // d_model
#define DI 1024          // d_inner
#define NH 8
#define HD 128
#define DS 16
#define CONVD 1056       // DI + 2*DSTATE
#define DPROJ 2088       // 2*DI + 2*DSTATE + NHEADS
#define NL 4
#define NE 131072        // 64 dirbh * 2048 state elems

typedef __hip_bfloat16 bf16;
typedef __attribute__((ext_vector_type(8))) short short8;
typedef __attribute__((ext_vector_type(4))) short short4v;
typedef __attribute__((ext_vector_type(4))) float f32x4;

#define AS_G __attribute__((address_space(1)))
#define AS_L __attribute__((address_space(3)))

static __device__ __forceinline__ float b2f_raw(short v){
  union { unsigned u; float f; } c; c.u = ((unsigned)(unsigned short)v) << 16; return c.f;
}
static __device__ __forceinline__ float u32_lo(unsigned u){
  union { unsigned u; float f; } c; c.u = u << 16; return c.f;
}
static __device__ __forceinline__ float u32_hi(unsigned u){
  union { unsigned u; float f; } c; c.u = u & 0xffff0000u; return c.f;
}
static __device__ __forceinline__ unsigned pack_bf16x2(float a, float b){
  unsigned lo = __bfloat16_as_ushort(__float2bfloat16(a));
  unsigned hi = __bfloat16_as_ushort(__float2bfloat16(b));
  return lo | (hi << 16);
}

// block-wide reduce of two values across 256 threads (4 waves)
static __device__ __forceinline__ void red2(float& a, float& b, float* sb){
  #pragma unroll
  for (int o = 32; o; o >>= 1){ a += __shfl_down(a, o); b += __shfl_down(b, o); }
  int w = threadIdx.x >> 6;
  if ((threadIdx.x & 63) == 0){ sb[w] = a; sb[4+w] = b; }
  __syncthreads();
  a = sb[0]+sb[1]+sb[2]+sb[3];
  b = sb[4]+sb[5]+sb[6]+sb[7];
}

// ---------------------------------------------------------------------------
// Dtype sniffing (proven-safe; unchanged).
// ---------------------------------------------------------------------------
__global__ __launch_bounds__(256) void detect_dtype(const void* x, int* flagp){
  __shared__ int cnt;
  if (threadIdx.x == 0) cnt = 0;
  __syncthreads();
  const bf16* p = (const bf16*)x;
  int bad = 0;
  for (int i = threadIdx.x; i < 32768; i += 256){
    float v = __bfloat162float(p[i]);
    if (!isfinite(v) || fabsf(v) > 1e4f) bad++;
  }
  atomicAdd(&cnt, bad);
  __syncthreads();
  if (threadIdx.x == 0) *flagp = (cnt > 100) ? 1 : 0;
}

__global__ __launch_bounds__(256) void convert_in(const void* src, bf16* dst, int n,
                                                  const int* flagp){
  int f = *flagp;
  for (int i = blockIdx.x*256 + threadIdx.x; i < n; i += gridDim.x*256){
    if (f) dst[i] = __float2bfloat16(((const float*)src)[i]);
    else   dst[i] = ((const bf16*)src)[i];
  }
}

// ---------------------------------------------------------------------------
// NT GEMM (r5 config, proven): MR=128, launch_bounds(256,4).
// 2-phase dbuf + zero-conflict XOR swizzle pair (measured 0 conflicts).
// GEMM arc closed after r0-r6: 4 schedules x 2 occupancies all ~500-580TF.
// OP=0 plain, OP=1 +bias(X[N]), OP=2 +residual(X[z][M][N], may alias C!),
// OP=3 plain + fp32 side-store of cols >= DPROJ-8 (dt_raw) into aux[z][M][8].
// ---------------------------------------------------------------------------
template<int OP>
__global__ __launch_bounds__(256,4) void gemm_nt(
    const bf16* __restrict__ A, const bf16* __restrict__ W0, const bf16* __restrict__ W1,
    bf16* C, const bf16* X, float* aux,
    int M, int N, int K, int lda, long sA, long sC)
{
  const int z = blockIdx.z;
  const bf16* Az = A + (long)z * sA;
  const bf16* W = z ? W1 : W0;
  const int m0 = blockIdx.x * 128, n0 = blockIdx.y * 128;
  __shared__ __align__(16) bf16 As[2][128*32];
  __shared__ __align__(16) bf16 Bs[2][128*32];
  const int tid  = threadIdx.x;
  const int lane = tid & 63, wv = tid >> 6;
  const int wmB = (wv >> 1)*64;               // wave row base in tile
  const int wnB = (wv & 1)*64;                // wave col base in tile
  const int quad = lane >> 4, l16 = lane & 15;
  const int srow = lane >> 2;                 // staging row within 16-row chunk
  const int skb  = (((lane & 3) ^ ((srow >> 1) & 3)) * 16);   // src-side swizzle
  const int rslot = ((quad ^ ((l16 >> 1) & 3)) * 16);         // read-side swizzle

  f32x4 acc[4][4];
  #pragma unroll
  for (int i=0;i<4;i++)
    #pragma unroll
    for (int j=0;j<4;j++) acc[i][j] = (f32x4){0.f,0.f,0.f,0.f};

  auto stage = [&](int k0, int buf){
    #pragma unroll
    for (int is = 0; is < 2; ++is){           // A tile: 128 rows
      int r = is*64 + wv*16 + srow;
      const char* gA = (const char*)(Az + (long)(m0 + r)*lda + k0) + skb;
      char* lA = (char*)(&As[buf][0]) + (long)(is*64 + wv*16)*64;
      __builtin_amdgcn_global_load_lds((const AS_G void*)gA, (AS_L void*)lA, 16, 0, 0);
    }
    #pragma unroll
    for (int is = 0; is < 2; ++is){           // B tile: 128 rows
      int r = is*64 + wv*16 + srow;
      int rn = n0 + r; rn = rn < N ? rn : N-1;  // clamp OOB weight rows
      const char* gB = (const char*)(W + (long)rn*K + k0) + skb;
      char* lB = (char*)(&Bs[buf][0]) + (long)(is*64 + wv*16)*64;
      __builtin_amdgcn_global_load_lds((const AS_G void*)gB, (AS_L void*)lB, 16, 0, 0);
    }
  };
  auto compute = [&](int buf){
    short8 af[4], bfr[4];
    #pragma unroll
    for (int mi=0;mi<4;mi++)
      af[mi]  = *(const short8*)((const char*)&As[buf][0] + (long)(wmB+mi*16+l16)*64 + rslot);
    #pragma unroll
    for (int ni=0;ni<4;ni++)
      bfr[ni] = *(const short8*)((const char*)&Bs[buf][0] + (long)(wnB+ni*16+l16)*64 + rslot);
    #pragma unroll
    for (int mi=0;mi<4;mi++)
      #pragma unroll
      for (int ni=0;ni<4;ni++)
        acc[mi][ni] = __builtin_amdgcn_mfma_f32_16x16x32_bf16(af[mi], bfr[ni], acc[mi][ni], 0, 0, 0);
  };

  stage(0, 0);
  __syncthreads();
  for (int k0 = 0; k0 < K; k0 += 64){
    if (k0 + 32 < K) stage(k0 + 32, 1);
    compute(0);
    __syncthreads();
    if (k0 + 64 < K) stage(k0 + 64, 0);
    compute(1);
    __syncthreads();
  }

  bf16* Cz = C + (long)z * sC;
  const bf16* Xz = (OP==2) ? (X + (long)z * sC) : X;
  #pragma unroll
  for (int mi=0;mi<4;mi++){
    #pragma unroll
    for (int ni=0;ni<4;ni++){
      #pragma unroll
      for (int r=0;r<4;r++){
        int row = m0 + wmB + mi*16 + quad*4 + r;
        int col = n0 + wnB + ni*16 + l16;
        if (col < N){
          float v = acc[mi][ni][r];
          if (OP==1) v += __bfloat162float(X[col]);
          if (OP==2) v += __bfloat162float(Xz[(long)row*N + col]);
          Cz[(long)row*N + col] = __float2bfloat16(v);
          if (OP==3 && col >= DPROJ-8)
            aux[(long)z*BT*8 + (long)row*8 + (col-(DPROJ-8))] = v;
        }
      }
    }
  }
}

// ---------------------------------------------------------------------------
// LayerNorm of embed output (512) -> h_f and time-reversed h_b
// ---------------------------------------------------------------------------
__global__ __launch_bounds__(256) void embed_ln(const bf16* __restrict__ hp,
    const bf16* __restrict__ w, const bf16* __restrict__ bb, bf16* __restrict__ h)
{
  __shared__ float sb[8];
  int bt = blockIdx.x; int b = bt >> 11, t = bt & 2047;
  const bf16* r = hp + (long)bt*DM;
  int c0 = threadIdx.x, c1 = threadIdx.x + 256;
  float v0 = __bfloat162float(r[c0]);
  float v1 = __bfloat162float(r[c1]);
  float s = v0+v1, ss = v0*v0+v1*v1;
  red2(s, ss, sb);
  float m = s / DM;
  float var = ss / DM - m*m;
  float rs = rsqrtf(fmaxf(var, 0.f) + 1e-5f);
  float a0 = (v0-m)*rs*__bfloat162float(w[c0]) + __bfloat162float(bb[c0]);
  float a1 = (v1-m)*rs*__bfloat162float(w[c1]) + __bfloat162float(bb[c1]);
  bf16* o0 = h + (long)bt*DM;
  bf16* o1 = h + ((long)BT + (long)b*TT + (TT-1-t)) * DM;
  o0[c0] = __float2bfloat16(a0); o0[c1] = __float2bfloat16(a1);
  o1[c0] = __float2bfloat16(a0); o1[c1] = __float2bfloat16(a1);
}

// ---------------------------------------------------------------------------
// Causal depthwise conv (K=4) + bias + SiLU — vectorized (round 5)
// ---------------------------------------------------------------------------
__global__ __launch_bounds__(256) void conv_silu(const bf16* __restrict__ zx,
    const bf16* __restrict__ cw0, const bf16* __restrict__ cw1,
    const bf16* __restrict__ cb0, const bf16* __restrict__ cb1,
    bf16* __restrict__ xbc)
{
  int bt = blockIdx.x, dir = blockIdx.y;
  int t = bt & 2047;
  const bf16* cw = dir ? cw1 : cw0;
  const bf16* cb = dir ? cb1 : cb0;
  const bf16* zr = zx + ((long)dir*BT + bt)*DPROJ + DI;  // row t, col 1024
  bf16* orow = xbc + ((long)dir*BT + bt)*CONVD;
  for (int cg = threadIdx.x; cg < CONVD/4; cg += 256){   // 264 groups of 4 ch
    int c = cg*4;
    short8 w01 = *(const short8*)(cw + c*4);       // ch c (j0..3), ch c+1
    short8 w23 = *(const short8*)(cw + c*4 + 8);   // ch c+2, ch c+3
    short4v bi = *(const short4v*)(cb + c);
    float acc[4];
    #pragma unroll
    for (int k=0;k<4;k++) acc[k] = b2f_raw(bi[k]);
    #pragma unroll
    for (int j=0;j<4;j++){
      if (t - 3 + j >= 0){
        short4v xv = *(const short4v*)(zr + (long)(j-3)*DPROJ + c);
        acc[0] = fmaf(b2f_raw(w01[j]),   b2f_raw(xv[0]), acc[0]);
        acc[1] = fmaf(b2f_raw(w01[4+j]), b2f_raw(xv[1]), acc[1]);
        acc[2] = fmaf(b2f_raw(w23[j]),   b2f_raw(xv[2]), acc[2]);
        acc[3] = fmaf(b2f_raw(w23[4+j]), b2f_raw(xv[3]), acc[3]);
      }
    }
    short4v ov;
    #pragma unroll
    for (int k=0;k<4;k++){
      float sg = 1.f / (1.f + expf(-acc[k]));
      ov[k] = (short)__bfloat16_as_ushort(__float2bfloat16(acc[k] * sg));
    }
    *(short4v*)(orow + c) = ov;
  }
}

// ---------------------------------------------------------------------------
// dt = softplus(dt_raw + bias); dA = exp(-exp(A_log)*dt); packed as float2
// ---------------------------------------------------------------------------
__global__ __launch_bounds__(256) void dt_kernel(const float* __restrict__ draw,
    const bf16* __restrict__ db0, const bf16* __restrict__ db1,
    const bf16* __restrict__ al0, const bf16* __restrict__ al1,
    float2* __restrict__ dadt)
{
  int idx = blockIdx.x*256 + threadIdx.x;   // 2*8192*8 = 131072 total
  int dir = idx >> 16, r = idx & 65535;
  int bt = r >> 3, h = r & 7;
  int b = bt >> 11, t = bt & 2047;
  float x = draw[idx] + __bfloat162float((dir?db1:db0)[h]);
  float sp = (x > 20.f) ? x : log1pf(expf(x));
  float a = expf(-expf(__bfloat162float((dir?al1:al0)[h])) * sp);
  long o = (((long)dir*BB + b)*NH + h)*TT + t;
  float2 v; v.x = a; v.y = sp;
  dadt[o] = v;
}

// ---------------------------------------------------------------------------
// Chunked selective scan. chunk_local: r8-proven (NCH=64 runtime, 2p/lane,
// coalesced 4B x-loads). chunk_apply_gate (round 13): FUSES gate+RMSNorm.
// Block = 512 thr = 8 waves = one (chunk, dir, b), wave = head h, lane owns
// 2 channels -> block holds the FULL 1024-ch row's y in registers at each t.
// Per 4-t group: scan-step + y, load z, g = y*silu(z), 4-batched block
// reduce of sum(g^2) (6 shfl + LDS + 2 barriers), scale by
// rsqrt(mean+eps)*rms_w, write g DIRECTLY into zx z-cols.
// Eliminates: gate_rms kernel (4 launches) + y write + y read (67 MB/layer).
// y is never materialized; next consumer of xbc is next layer's conv which
// overwrites it fully. SC layout identical to chunk_local's writes.
// ---------------------------------------------------------------------------
#define CLG_LOAD(G, T0) do{ \
  _Pragma("unroll") \
  for (int _i=0;_i<4;_i++){ \
    const bf16* _rr = xr + (long)((T0)+_i)*CONVD; \
    G##x[_i]  = *(const unsigned*)(_rr + xoff); \
    G##B0[_i] = *(const short8*)(_rr + DI); \
    G##B1[_i] = *(const short8*)(_rr + DI + 8); \
    G##d[_i]  = ddr[(T0)+_i]; \
  } }while(0)

#define CLG_STEP(G) do{ \
  _Pragma("unroll") \
  for (int _i=0;_i<4;_i++){ \
    float _da = G##d[_i].x, _dt = G##d[_i].y; \
    float _x0 = u32_lo(G##x[_i]), _x1 = u32_hi(G##x[_i]); \
    float _xd0 = _x0*_dt, _xd1 = _x1*_dt; \
    _Pragma("unroll") \
    for (int _n=0;_n<8;_n++){ \
      float _b = b2f_raw(G##B0[_i][_n]); \
      s0[_n] = fmaf(_da, s0[_n], _xd0*_b); \
      s1[_n] = fmaf(_da, s1[_n], _xd1*_b); \
      float _b2 = b2f_raw(G##B1[_i][_n]); \
      s0[8+_n] = fmaf(_da, s0[8+_n], _xd0*_b2); \
      s1[8+_n] = fmaf(_da, s1[8+_n], _xd1*_b2); \
    } \
    pacc *= _da; \
  } }while(0)

__global__ __launch_bounds__(256,1) void chunk_local(const bf16* __restrict__ xbc,
    const float2* __restrict__ dadt, float* __restrict__ SC, float* __restrict__ Pc,
    int cl, int nch)
{
  int c = blockIdx.x;
  int dbh = blockIdx.y*4 + (threadIdx.x >> 6);
  int lane = threadIdx.x & 63;
  int dir = dbh >> 5, b = (dbh >> 3) & 3, h = dbh & 7;
  const bf16* xr = xbc + ((long)dir*BT + (long)b*TT) * CONVD;
  const float2* ddr = dadt + (long)dbh*TT;
  const int xoff = h*HD + lane*2;
  float s0[16], s1[16];
  #pragma unroll
  for (int n=0;n<16;n++){ s0[n]=0.f; s1[n]=0.f; }
  float pacc = 1.f;
  const int c0 = c*cl;

  unsigned Ax[4], Bx[4]; short8 AB0[4], AB1[4], BB0[4], BB1[4]; float2 Ad[4], Bd[4];
  CLG_LOAD(A, c0);
  for (int t0 = c0; t0 < c0+cl; t0 += 8){
    CLG_LOAD(B, t0+4);
    CLG_STEP(A);
    if (t0+8 < c0+cl) CLG_LOAD(A, t0+8);
    CLG_STEP(B);
  }
  float* sc = SC + (long)c*NE + (long)dbh*2048 + lane*32;
  #pragma unroll
  for (int n=0;n<16;n++){ sc[n] = s0[n]; sc[16+n] = s1[n]; }
  if (lane == 0) Pc[dbh*nch + c] = pacc;
}

template<int NCH>
__global__ __launch_bounds__(256) void chunk_combine(float* __restrict__ SC,
    const float* __restrict__ Pc)
{
  int e = blockIdx.x*256 + threadIdx.x;   // 131072 total
  int dbh = e >> 11;
  float s = 0.f;
  #pragma unroll
  for (int c=0;c<NCH;c++){
    float tmp = SC[(long)c*NE + e];
    SC[(long)c*NE + e] = s;               // exclusive scan in place -> S_init
    s = Pc[dbh*NCH + c]*s + tmp;
  }
}

__global__ __launch_bounds__(512,2) void chunk_apply_gate(
    const bf16* __restrict__ xbc, bf16* __restrict__ zx,
    const float2* __restrict__ dadt, const float* __restrict__ SC,
    const bf16* __restrict__ D0, const bf16* __restrict__ D1,
    const bf16* __restrict__ rw0, const bf16* __restrict__ rw1, int cl)
{
  __shared__ float sb[8][4];
  int c = blockIdx.x;
  int db = blockIdx.y;                      // dir*4 + b
  int dir = db >> 2, b = db & 3;
  int h = threadIdx.x >> 6;                 // wave = head
  int lane = threadIdx.x & 63;
  int dbh = dir*32 + b*8 + h;
  const bf16* xr = xbc + ((long)dir*BT + (long)b*TT) * CONVD;
  bf16* zrow = zx + ((long)dir*BT + (long)b*TT) * DPROJ;
  const float2* ddr = dadt + (long)dbh*TT;
  const int xoff = h*HD + lane*2;           // 2 channels of head h
  float Dv = __bfloat162float(dir ? D1[h] : D0[h]);
  const bf16* rw = dir ? rw1 : rw0;
  float rwl = __bfloat162float(rw[xoff]);
  float rwh = __bfloat162float(rw[xoff+1]);
  const float* sc = SC + (long)c*NE + (long)dbh*2048 + lane*32;
  float s0[16], s1[16];
  #pragma unroll
  for (int n=0;n<16;n++){ s0[n] = sc[n]; s1[n] = sc[16+n]; }
  const int c0 = c*cl;

  for (int t0 = c0; t0 < c0+cl; t0 += 4){
    float gl[4], gh[4], sum2[4];
    #pragma unroll
    for (int i=0;i<4;i++){
      const bf16* rr = xr + (long)(t0+i)*CONVD;
      unsigned xv = *(const unsigned*)(rr + xoff);
      short8 B0 = *(const short8*)(rr + DI);
      short8 B1 = *(const short8*)(rr + DI + 8);
      short8 C0 = *(const short8*)(rr + DI + DS);
      short8 C1 = *(const short8*)(rr + DI + DS + 8);
      unsigned zv = *(const unsigned*)(zrow + (long)(t0+i)*DPROJ + xoff);
      float2 dd = ddr[t0+i];
      float da = dd.x, dt = dd.y;
      float x0 = u32_lo(xv), x1 = u32_hi(xv);
      float xd0 = x0*dt, xd1 = x1*dt;
      float a0 = 0.f, a1 = 0.f;
      #pragma unroll
      for (int n=0;n<8;n++){
        float bb0 = b2f_raw(B0[n]), cc0 = b2f_raw(C0[n]);
        s0[n] = fmaf(da, s0[n], xd0*bb0);
        s1[n] = fmaf(da, s1[n], xd1*bb0);
        a0 = fmaf(s0[n], cc0, a0);
        a1 = fmaf(s1[n], cc0, a1);
        float bb1 = b2f_raw(B1[n]), cc1 = b2f_raw(C1[n]);
        s0[8+n] = fmaf(da, s0[8+n], xd0*bb1);
        s1[8+n] = fmaf(da, s1[8+n], xd1*bb1);
        a0 = fmaf(s0[8+n], cc1, a0);
        a1 = fmaf(s1[8+n], cc1, a1);
      }
      float y0 = a0 + Dv*x0, y1 = a1 + Dv*x1;
      float z0 = u32_lo(zv), z1 = u32_hi(zv);
      float g0 = y0 * z0 * (1.f/(1.f+expf(-z0)));
      float g1 = y1 * z1 * (1.f/(1.f+expf(-z1)));
      gl[i] = g0; gh[i] = g1;
      sum2[i] = g0*g0 + g1*g1;
    }
    // 4-batched block reduce over 512 threads (= full 1024-ch row per t)
    #pragma unroll
    for (int o=32;o;o>>=1){
      #pragma unroll
      for (int i=0;i<4;i++) sum2[i] += __shfl_down(sum2[i], o);
    }
    if (lane == 0){
      #pragma unroll
      for (int i=0;i<4;i++) sb[h][i] = sum2[i];
    }
    __syncthreads();
    float scl[4];
    #pragma unroll
    for (int i=0;i<4;i++){
      float tot = 0.f;
      #pragma unroll
      for (int w=0;w<8;w++) tot += sb[w][i];
      scl[i] = rsqrtf(tot*(1.f/DI) + 1e-5f);
    }
    __syncthreads();   // sb reads done before next group's writes
    #pragma unroll
    for (int i=0;i<4;i++)
      *(unsigned*)(zrow + (long)(t0+i)*DPROJ + xoff) =
          pack_bf16x2(gl[i]*scl[i]*rwl, gh[i]*scl[i]*rwh);
  }
}

// ---------------------------------------------------------------------------
// Final LN over concat(h_f[b,t], h_b[b,T-1-t]) (1024) -> d_out
// ---------------------------------------------------------------------------
__global__ __launch_bounds__(256) void final_ln(const bf16* __restrict__ h,
    const bf16* __restrict__ lw, const bf16* __restrict__ lb, void* out,
    int mode, const int* flagp)
{
  __shared__ float sb[8];
  int bt = blockIdx.x; int b = bt >> 11, t = bt & 2047;
  int f32out = mode ? *flagp : 0;
  const bf16* rf = h + (long)bt*DM;
  const bf16* rb = h + ((long)BT + (long)b*TT + (TT-1-t))*DM;
  float v[4], s = 0.f, ss = 0.f;
  #pragma unroll
  for (int i=0;i<4;i++){
    int c = threadIdx.x + i*256;
    v[i] = __bfloat162float(c < DM ? rf[c] : rb[c-DM]);
    s += v[i]; ss += v[i]*v[i];
  }
  red2(s, ss, sb);
  float m = s / (2*DM);
  float var = ss / (2*DM) - m*m;
  float rs = rsqrtf(fmaxf(var, 0.f) + 1e-5f);
  #pragma unroll
  for (int i=0;i<4;i++){
    int c = threadIdx.x + i*256;
    float o = (v[i]-m)*rs*__bfloat162float(lw[c]) + __bfloat162float(lb[c]);
    if (f32out) ((float*)out)[(long)bt*(2*DM) + c] = o;
    else        ((bf16*)out)[(long)bt*(2*DM) + c] = __float2bfloat16(o);
  }
}

// ---------------------------------------------------------------------------
extern "C" void kernel_launch(void* const* d_in, const int* in_sizes, int n_in,
                              void* d_out, int out_size, void* d_ws, size_t ws_size,
                              hipStream_t stream)
{
  char* wsp = (char*)d_ws;
  auto take = [&](size_t bytes){ char* p = wsp; wsp += (bytes + 63) & ~(size_t)63; return p; };
  int*   flagp = (int*)  take(4);
  bf16*  h     = (bf16*) take((size_t)2*BT*DM*2);      // 16.78 MB
  bf16*  zx    = (bf16*) take((size_t)2*BT*DPROJ*2);   // 68.42 MB (z gated in place)
  bf16*  xbc   = (bf16*) take((size_t)2*BT*CONVD*2);   // 34.60 MB
  float2* dadt = (float2*)take((size_t)2*BB*NH*TT*8);  // 1.05 MB
  float* draw  = (float*)take((size_t)2*BT*NH*4);      // 0.52 MB
  float* Pc    = (float*)take((size_t)64*64*4);        // 16 KB (max NCH=64)
  char* preCanon = wsp;                                // direct-mode SC base

  static const int cnt[23] = {
    BT*256, DM*256, DM, DM, DM, 2*DM, 2*DM,
    NL*DPROJ*DM, NL*CONVD*4, NL*CONVD, NL*NH, NL*NH, NL*NH, NL*DI, NL*DM*DI,
    NL*DPROJ*DM, NL*CONVD*4, NL*CONVD, NL*NH, NL*NH, NL*NH, NL*DI, NL*DM*DI };
  bf16* canon[23];
  for (int i = 0; i < 23; ++i) canon[i] = (bf16*)take((size_t)cnt[i]*2);
  char* postCanon = wsp;

  // SC at workspace tail; chunk count picked to fit (16 == legacy config).
  const size_t scUnit = (size_t)NE*4;                  // 512 KB per chunk
  size_t usedFull   = (size_t)(postCanon - (char*)d_ws);
  size_t usedDirect = (size_t)(preCanon  - (char*)d_ws);
  int convMode, NCHR; float* SC;
  if      (ws_size >= usedFull + 64*scUnit){ convMode=1; NCHR=64; SC=(float*)postCanon; }
  else if (ws_size >= usedFull + 32*scUnit){ convMode=1; NCHR=32; SC=(float*)postCanon; }
  else if (ws_size >= usedFull + 16*scUnit){ convMode=1; NCHR=16; SC=(float*)postCanon; }
  else {
    convMode = 0;
    if      (ws_size >= usedDirect + 64*scUnit) NCHR=64;
    else if (ws_size >= usedDirect + 32*scUnit) NCHR=32;
    else                                        NCHR=16;
    SC = (float*)preCanon;                             // canon region unused
  }
  const int CLR = TT / NCHR;

  const bf16* in[23];
  if (convMode){
    detect_dtype<<<1,256,0,stream>>>(d_in[0], flagp);
    for (int i = 0; i < 23; ++i){
      int grid = (cnt[i] + 255)/256; if (grid > 2048) grid = 2048;
      convert_in<<<grid,256,0,stream>>>(d_in[i], canon[i], cnt[i], flagp);
      in[i] = canon[i];
    }
  } else {
    for (int i = 0; i < 23; ++i) in[i] = (const bf16*)d_in[i];
  }

  const bf16* x       = in[0];
  const bf16* embed_w = in[1];
  const bf16* embed_b = in[2];
  const bf16* ln1_w   = in[3];
  const bf16* ln1_b   = in[4];
  const bf16* lnout_w = in[5];
  const bf16* lnout_b = in[6];
  const bf16* in_w[2]   = {in[7],  in[15]};
  const bf16* conv_w[2] = {in[8],  in[16]};
  const bf16* conv_b[2] = {in[9],  in[17]};
  const bf16* dt_b[2]   = {in[10], in[18]};
  const bf16* A_log[2]  = {in[11], in[19]};
  const bf16* Dp[2]     = {in[12], in[20]};
  const bf16* rms_w[2]  = {in[13], in[21]};
  const bf16* out_w[2]  = {in[14], in[22]};

  bf16* hpre = xbc;   // embed output parks in xbc (free until layer-0 conv)

  gemm_nt<1><<<dim3(64,4,1),256,0,stream>>>(x, embed_w, embed_w, hpre, embed_b, nullptr,
                                            BT, DM, 256, 256, 0, 0);
  embed_ln<<<dim3(BT),256,0,stream>>>(hpre, ln1_w, ln1_b, h);

  for (int i = 0; i < NL; ++i){
    gemm_nt<3><<<dim3(64,17,2),256,0,stream>>>(h, in_w[0]+(size_t)i*DPROJ*DM, in_w[1]+(size_t)i*DPROJ*DM,
        zx, nullptr, draw, BT, DPROJ, DM, DM, (long)BT*DM, (long)BT*DPROJ);
    conv_silu<<<dim3(BT,2),256,0,stream>>>(zx, conv_w[0]+(size_t)i*CONVD*4, conv_w[1]+(size_t)i*CONVD*4,
        conv_b[0]+(size_t)i*CONVD, conv_b[1]+(size_t)i*CONVD, xbc);
    dt_kernel<<<dim3(512),256,0,stream>>>(draw, dt_b[0]+i*NH, dt_b[1]+i*NH,
        A_log[0]+i*NH, A_log[1]+i*NH, dadt);
    chunk_local<<<dim3(NCHR,16),256,0,stream>>>(xbc, dadt, SC, Pc, CLR, NCHR);
    if      (NCHR == 64) chunk_combine<64><<<dim3(NE/256),256,0,stream>>>(SC, Pc);
    else if (NCHR == 32) chunk_combine<32><<<dim3(NE/256),256,0,stream>>>(SC, Pc);
    else                 chunk_combine<16><<<dim3(NE/256),256,0,stream>>>(SC, Pc);
    chunk_apply_gate<<<dim3(NCHR,8),512,0,stream>>>(xbc, zx, dadt, SC,
        Dp[0]+i*NH, Dp[1]+i*NH, rms_w[0]+(size_t)i*DI, rms_w[1]+(size_t)i*DI, CLR);
    gemm_nt<2><<<dim3(64,4,2),256,0,stream>>>(zx, out_w[0]+(size_t)i*DM*DI, out_w[1]+(size_t)i*DM*DI,
        h, h, nullptr, BT, DM, DI, DPROJ, (long)BT*DPROJ, (long)BT*DM);
  }

  final_ln<<<dim3(BT),256,0,stream>>>(h, lnout_w, lnout_b, d_out, convMode, flagp);
  (void)in_sizes; (void)n_in; (void)out_size;
}

// Round 10
// 1136.716 us; speedup vs baseline: 1.0767x; 1.0767x over previous
//
#include <hip/hip_runtime.h>
#include <hip/hip_bf16.h>
#include <math.h>

// Problem constants
#define BB 4
#define TT 2048
#define BT 8192          // B*T rows
#define DM 512           // d_model
#define DI 1024          // d_inner
#define NH 8
#define HD 128
#define DS 16
#define CONVD 1056       // DI + 2*DSTATE
#define DPROJ 2088       // 2*DI + 2*DSTATE + NHEADS
#define NL 4
#define NE 131072        // 64 dirbh * 2048 state elems

typedef __hip_bfloat16 bf16;
typedef __attribute__((ext_vector_type(8))) short short8;
typedef __attribute__((ext_vector_type(4))) short short4v;
typedef __attribute__((ext_vector_type(4))) float f32x4;

#define AS_G __attribute__((address_space(1)))
#define AS_L __attribute__((address_space(3)))

static __device__ __forceinline__ float b2f_raw(short v){
  union { unsigned u; float f; } c; c.u = ((unsigned)(unsigned short)v) << 16; return c.f;
}
static __device__ __forceinline__ float u32_lo(unsigned u){
  union { unsigned u; float f; } c; c.u = u << 16; return c.f;
}
static __device__ __forceinline__ float u32_hi(unsigned u){
  union { unsigned u; float f; } c; c.u = u & 0xffff0000u; return c.f;
}
static __device__ __forceinline__ unsigned pack_bf16x2(float a, float b){
  unsigned lo = __bfloat16_as_ushort(__float2bfloat16(a));
  unsigned hi = __bfloat16_as_ushort(__float2bfloat16(b));
  return lo | (hi << 16);
}

// block-wide reduce of two values across 256 threads (4 waves)
static __device__ __forceinline__ void red2(float& a, float& b, float* sb){
  #pragma unroll
  for (int o = 32; o; o >>= 1){ a += __shfl_down(a, o); b += __shfl_down(b, o); }
  int w = threadIdx.x >> 6;
  if ((threadIdx.x & 63) == 0){ sb[w] = a; sb[4+w] = b; }
  __syncthreads();
  a = sb[0]+sb[1]+sb[2]+sb[3];
  b = sb[4]+sb[5]+sb[6]+sb[7];
}

// ---------------------------------------------------------------------------
// Dtype sniffing (proven-safe; unchanged).
// ---------------------------------------------------------------------------
__global__ __launch_bounds__(256) void detect_dtype(const void* x, int* flagp){
  __shared__ int cnt;
  if (threadIdx.x == 0) cnt = 0;
  __syncthreads();
  const bf16* p = (const bf16*)x;
  int bad = 0;
  for (int i = threadIdx.x; i < 32768; i += 256){
    float v = __bfloat162float(p[i]);
    if (!isfinite(v) || fabsf(v) > 1e4f) bad++;
  }
  atomicAdd(&cnt, bad);
  __syncthreads();
  if (threadIdx.x == 0) *flagp = (cnt > 100) ? 1 : 0;
}

__global__ __launch_bounds__(256) void convert_in(const void* src, bf16* dst, int n,
                                                  const int* flagp){
  int f = *flagp;
  for (int i = blockIdx.x*256 + threadIdx.x; i < n; i += gridDim.x*256){
    if (f) dst[i] = __float2bfloat16(((const float*)src)[i]);
    else   dst[i] = ((const bf16*)src)[i];
  }
}

// ---------------------------------------------------------------------------
// NT GEMM (r5 config, proven): MR=128, launch_bounds(256,4).
// 2-phase dbuf + zero-conflict XOR swizzle pair (measured 0 conflicts).
// OP=0 plain, OP=1 +bias(X[N]), OP=2 +residual(X[z][M][N], may alias C!),
// OP=3 plain + fp32 side-store of cols >= DPROJ-8 (dt_raw) into aux[z][M][8],
// OP=4 (round 14) v = acc*aux[z*BT+row] + residual — deferred RMS scale:
//   out = scl(row)*(graw @ W^T) + h, scl from rms_scl kernel. Removes the
//   block-reduce (and its barriers) from chunk_apply_gate entirely.
// ---------------------------------------------------------------------------
template<int OP>
__global__ __launch_bounds__(256,4) void gemm_nt(
    const bf16* __restrict__ A, const bf16* __restrict__ W0, const bf16* __restrict__ W1,
    bf16* C, const bf16* X, float* aux,
    int M, int N, int K, int lda, long sA, long sC)
{
  const int z = blockIdx.z;
  const bf16* Az = A + (long)z * sA;
  const bf16* W = z ? W1 : W0;
  const int m0 = blockIdx.x * 128, n0 = blockIdx.y * 128;
  __shared__ __align__(16) bf16 As[2][128*32];
  __shared__ __align__(16) bf16 Bs[2][128*32];
  const int tid  = threadIdx.x;
  const int lane = tid & 63, wv = tid >> 6;
  const int wmB = (wv >> 1)*64;               // wave row base in tile
  const int wnB = (wv & 1)*64;                // wave col base in tile
  const int quad = lane >> 4, l16 = lane & 15;
  const int srow = lane >> 2;                 // staging row within 16-row chunk
  const int skb  = (((lane & 3) ^ ((srow >> 1) & 3)) * 16);   // src-side swizzle
  const int rslot = ((quad ^ ((l16 >> 1) & 3)) * 16);         // read-side swizzle

  f32x4 acc[4][4];
  #pragma unroll
  for (int i=0;i<4;i++)
    #pragma unroll
    for (int j=0;j<4;j++) acc[i][j] = (f32x4){0.f,0.f,0.f,0.f};

  auto stage = [&](int k0, int buf){
    #pragma unroll
    for (int is = 0; is < 2; ++is){           // A tile: 128 rows
      int r = is*64 + wv*16 + srow;
      const char* gA = (const char*)(Az + (long)(m0 + r)*lda + k0) + skb;
      char* lA = (char*)(&As[buf][0]) + (long)(is*64 + wv*16)*64;
      __builtin_amdgcn_global_load_lds((const AS_G void*)gA, (AS_L void*)lA, 16, 0, 0);
    }
    #pragma unroll
    for (int is = 0; is < 2; ++is){           // B tile: 128 rows
      int r = is*64 + wv*16 + srow;
      int rn = n0 + r; rn = rn < N ? rn : N-1;  // clamp OOB weight rows
      const char* gB = (const char*)(W + (long)rn*K + k0) + skb;
      char* lB = (char*)(&Bs[buf][0]) + (long)(is*64 + wv*16)*64;
      __builtin_amdgcn_global_load_lds((const AS_G void*)gB, (AS_L void*)lB, 16, 0, 0);
    }
  };
  auto compute = [&](int buf){
    short8 af[4], bfr[4];
    #pragma unroll
    for (int mi=0;mi<4;mi++)
      af[mi]  = *(const short8*)((const char*)&As[buf][0] + (long)(wmB+mi*16+l16)*64 + rslot);
    #pragma unroll
    for (int ni=0;ni<4;ni++)
      bfr[ni] = *(const short8*)((const char*)&Bs[buf][0] + (long)(wnB+ni*16+l16)*64 + rslot);
    #pragma unroll
    for (int mi=0;mi<4;mi++)
      #pragma unroll
      for (int ni=0;ni<4;ni++)
        acc[mi][ni] = __builtin_amdgcn_mfma_f32_16x16x32_bf16(af[mi], bfr[ni], acc[mi][ni], 0, 0, 0);
  };

  stage(0, 0);
  __syncthreads();
  for (int k0 = 0; k0 < K; k0 += 64){
    if (k0 + 32 < K) stage(k0 + 32, 1);
    compute(0);
    __syncthreads();
    if (k0 + 64 < K) stage(k0 + 64, 0);
    compute(1);
    __syncthreads();
  }

  bf16* Cz = C + (long)z * sC;
  const bf16* Xz = (OP==2 || OP==4) ? (X + (long)z * sC) : X;
  #pragma unroll
  for (int mi=0;mi<4;mi++){
    #pragma unroll
    for (int ni=0;ni<4;ni++){
      #pragma unroll
      for (int r=0;r<4;r++){
        int row = m0 + wmB + mi*16 + quad*4 + r;
        int col = n0 + wnB + ni*16 + l16;
        if (col < N){
          float v = acc[mi][ni][r];
          if (OP==1) v += __bfloat162float(X[col]);
          if (OP==2) v += __bfloat162float(Xz[(long)row*N + col]);
          if (OP==4){
            v *= aux[(long)z*BT + row];
            v += __bfloat162float(Xz[(long)row*N + col]);
          }
          Cz[(long)row*N + col] = __float2bfloat16(v);
          if (OP==3 && col >= DPROJ-8)
            aux[(long)z*BT*8 + (long)row*8 + (col-(DPROJ-8))] = v;
        }
      }
    }
  }
}

// ---------------------------------------------------------------------------
// LayerNorm of embed output (512) -> h_f and time-reversed h_b
// ---------------------------------------------------------------------------
__global__ __launch_bounds__(256) void embed_ln(const bf16* __restrict__ hp,
    const bf16* __restrict__ w, const bf16* __restrict__ bb, bf16* __restrict__ h)
{
  __shared__ float sb[8];
  int bt = blockIdx.x; int b = bt >> 11, t = bt & 2047;
  const bf16* r = hp + (long)bt*DM;
  int c0 = threadIdx.x, c1 = threadIdx.x + 256;
  float v0 = __bfloat162float(r[c0]);
  float v1 = __bfloat162float(r[c1]);
  float s = v0+v1, ss = v0*v0+v1*v1;
  red2(s, ss, sb);
  float m = s / DM;
  float var = ss / DM - m*m;
  float rs = rsqrtf(fmaxf(var, 0.f) + 1e-5f);
  float a0 = (v0-m)*rs*__bfloat162float(w[c0]) + __bfloat162float(bb[c0]);
  float a1 = (v1-m)*rs*__bfloat162float(w[c1]) + __bfloat162float(bb[c1]);
  bf16* o0 = h + (long)bt*DM;
  bf16* o1 = h + ((long)BT + (long)b*TT + (TT-1-t)) * DM;
  o0[c0] = __float2bfloat16(a0); o0[c1] = __float2bfloat16(a1);
  o1[c0] = __float2bfloat16(a0); o1[c1] = __float2bfloat16(a1);
}

// ---------------------------------------------------------------------------
// Causal depthwise conv (K=4) + bias + SiLU — vectorized (round 5)
// ---------------------------------------------------------------------------
__global__ __launch_bounds__(256) void conv_silu(const bf16* __restrict__ zx,
    const bf16* __restrict__ cw0, const bf16* __restrict__ cw1,
    const bf16* __restrict__ cb0, const bf16* __restrict__ cb1,
    bf16* __restrict__ xbc)
{
  int bt = blockIdx.x, dir = blockIdx.y;
  int t = bt & 2047;
  const bf16* cw = dir ? cw1 : cw0;
  const bf16* cb = dir ? cb1 : cb0;
  const bf16* zr = zx + ((long)dir*BT + bt)*DPROJ + DI;  // row t, col 1024
  bf16* orow = xbc + ((long)dir*BT + bt)*CONVD;
  for (int cg = threadIdx.x; cg < CONVD/4; cg += 256){   // 264 groups of 4 ch
    int c = cg*4;
    short8 w01 = *(const short8*)(cw + c*4);       // ch c (j0..3), ch c+1
    short8 w23 = *(const short8*)(cw + c*4 + 8);   // ch c+2, ch c+3
    short4v bi = *(const short4v*)(cb + c);
    float acc[4];
    #pragma unroll
    for (int k=0;k<4;k++) acc[k] = b2f_raw(bi[k]);
    #pragma unroll
    for (int j=0;j<4;j++){
      if (t - 3 + j >= 0){
        short4v xv = *(const short4v*)(zr + (long)(j-3)*DPROJ + c);
        acc[0] = fmaf(b2f_raw(w01[j]),   b2f_raw(xv[0]), acc[0]);
        acc[1] = fmaf(b2f_raw(w01[4+j]), b2f_raw(xv[1]), acc[1]);
        acc[2] = fmaf(b2f_raw(w23[j]),   b2f_raw(xv[2]), acc[2]);
        acc[3] = fmaf(b2f_raw(w23[4+j]), b2f_raw(xv[3]), acc[3]);
      }
    }
    short4v ov;
    #pragma unroll
    for (int k=0;k<4;k++){
      float sg = 1.f / (1.f + expf(-acc[k]));
      ov[k] = (short)__bfloat16_as_ushort(__float2bfloat16(acc[k] * sg));
    }
    *(short4v*)(orow + c) = ov;
  }
}

// ---------------------------------------------------------------------------
// dt = softplus(dt_raw + bias); dA = exp(-exp(A_log)*dt); packed as float2
// ---------------------------------------------------------------------------
__global__ __launch_bounds__(256) void dt_kernel(const float* __restrict__ draw,
    const bf16* __restrict__ db0, const bf16* __restrict__ db1,
    const bf16* __restrict__ al0, const bf16* __restrict__ al1,
    float2* __restrict__ dadt)
{
  int idx = blockIdx.x*256 + threadIdx.x;   // 2*8192*8 = 131072 total
  int dir = idx >> 16, r = idx & 65535;
  int bt = r >> 3, h = r & 7;
  int b = bt >> 11, t = bt & 2047;
  float x = draw[idx] + __bfloat162float((dir?db1:db0)[h]);
  float sp = (x > 20.f) ? x : log1pf(expf(x));
  float a = expf(-expf(__bfloat162float((dir?al1:al0)[h])) * sp);
  long o = (((long)dir*BB + b)*NH + h)*TT + t;
  float2 v; v.x = a; v.y = sp;
  dadt[o] = v;
}

// ---------------------------------------------------------------------------
// Chunked selective scan. chunk_local: r8-proven (NCH=64 runtime, 2p/lane,
// coalesced 4B x-loads). chunk_apply_gate (round 14): BARRIER-FREE fused
// gate. r9 post-mortem: the in-kernel RMS block-reduce (2 barriers / 4t,
// 8-wave lockstep) held the kernel at its latency-bound 1.15 TB/s = 75.8us.
// Fix: defer the scale. Kernel writes UNSCALED graw = y*silu(z)*rw into the
// z-cols of zx (lane-local) + per-wave partial sum(g^2) -> psum[row][head]
// (6 shfl + 1 store, no LDS, no barriers). rms_scl computes
// scl[row] = rsqrt(mean+eps); out_proj (OP=4) multiplies acc*scl[row] in the
// epilogue (linear algebra: out = scl*(graw@W^T) + h).
// ---------------------------------------------------------------------------
#define CLG_LOAD(G, T0) do{ \
  _Pragma("unroll") \
  for (int _i=0;_i<4;_i++){ \
    const bf16* _rr = xr + (long)((T0)+_i)*CONVD; \
    G##x[_i]  = *(const unsigned*)(_rr + xoff); \
    G##B0[_i] = *(const short8*)(_rr + DI); \
    G##B1[_i] = *(const short8*)(_rr + DI + 8); \
    G##d[_i]  = ddr[(T0)+_i]; \
  } }while(0)

#define CLG_STEP(G) do{ \
  _Pragma("unroll") \
  for (int _i=0;_i<4;_i++){ \
    float _da = G##d[_i].x, _dt = G##d[_i].y; \
    float _x0 = u32_lo(G##x[_i]), _x1 = u32_hi(G##x[_i]); \
    float _xd0 = _x0*_dt, _xd1 = _x1*_dt; \
    _Pragma("unroll") \
    for (int _n=0;_n<8;_n++){ \
      float _b = b2f_raw(G##B0[_i][_n]); \
      s0[_n] = fmaf(_da, s0[_n], _xd0*_b); \
      s1[_n] = fmaf(_da, s1[_n], _xd1*_b); \
      float _b2 = b2f_raw(G##B1[_i][_n]); \
      s0[8+_n] = fmaf(_da, s0[8+_n], _xd0*_b2); \
      s1[8+_n] = fmaf(_da, s1[8+_n], _xd1*_b2); \
    } \
    pacc *= _da; \
  } }while(0)

__global__ __launch_bounds__(256,1) void chunk_local(const bf16* __restrict__ xbc,
    const float2* __restrict__ dadt, float* __restrict__ SC, float* __restrict__ Pc,
    int cl, int nch)
{
  int c = blockIdx.x;
  int dbh = blockIdx.y*4 + (threadIdx.x >> 6);
  int lane = threadIdx.x & 63;
  int dir = dbh >> 5, b = (dbh >> 3) & 3, h = dbh & 7;
  const bf16* xr = xbc + ((long)dir*BT + (long)b*TT) * CONVD;
  const float2* ddr = dadt + (long)dbh*TT;
  const int xoff = h*HD + lane*2;
  float s0[16], s1[16];
  #pragma unroll
  for (int n=0;n<16;n++){ s0[n]=0.f; s1[n]=0.f; }
  float pacc = 1.f;
  const int c0 = c*cl;

  unsigned Ax[4], Bx[4]; short8 AB0[4], AB1[4], BB0[4], BB1[4]; float2 Ad[4], Bd[4];
  CLG_LOAD(A, c0);
  for (int t0 = c0; t0 < c0+cl; t0 += 8){
    CLG_LOAD(B, t0+4);
    CLG_STEP(A);
    if (t0+8 < c0+cl) CLG_LOAD(A, t0+8);
    CLG_STEP(B);
  }
  float* sc = SC + (long)c*NE + (long)dbh*2048 + lane*32;
  #pragma unroll
  for (int n=0;n<16;n++){ sc[n] = s0[n]; sc[16+n] = s1[n]; }
  if (lane == 0) Pc[dbh*nch + c] = pacc;
}

template<int NCH>
__global__ __launch_bounds__(256) void chunk_combine(float* __restrict__ SC,
    const float* __restrict__ Pc)
{
  int e = blockIdx.x*256 + threadIdx.x;   // 131072 total
  int dbh = e >> 11;
  float s = 0.f;
  #pragma unroll
  for (int c=0;c<NCH;c++){
    float tmp = SC[(long)c*NE + e];
    SC[(long)c*NE + e] = s;               // exclusive scan in place -> S_init
    s = Pc[dbh*NCH + c]*s + tmp;
  }
}

__global__ __launch_bounds__(512,2) void chunk_apply_gate(
    const bf16* __restrict__ xbc, bf16* __restrict__ zx,
    const float2* __restrict__ dadt, const float* __restrict__ SC,
    const bf16* __restrict__ D0, const bf16* __restrict__ D1,
    const bf16* __restrict__ rw0, const bf16* __restrict__ rw1,
    float* __restrict__ psum, int cl)
{
  int c = blockIdx.x;
  int db = blockIdx.y;                      // dir*4 + b
  int dir = db >> 2, b = db & 3;
  int h = threadIdx.x >> 6;                 // wave = head
  int lane = threadIdx.x & 63;
  int dbh = dir*32 + b*8 + h;
  const bf16* xr = xbc + ((long)dir*BT + (long)b*TT) * CONVD;
  bf16* zrow = zx + ((long)dir*BT + (long)b*TT) * DPROJ;
  const long rowB = (long)dir*BT + (long)b*TT;   // global row base
  const float2* ddr = dadt + (long)dbh*TT;
  const int xoff = h*HD + lane*2;           // 2 channels of head h
  float Dv = __bfloat162float(dir ? D1[h] : D0[h]);
  const bf16* rw = dir ? rw1 : rw0;
  float rwl = __bfloat162float(rw[xoff]);
  float rwh = __bfloat162float(rw[xoff+1]);
  const float* sc = SC + (long)c*NE + (long)dbh*2048 + lane*32;
  float s0[16], s1[16];
  #pragma unroll
  for (int n=0;n<16;n++){ s0[n] = sc[n]; s1[n] = sc[16+n]; }
  const int c0 = c*cl;

  for (int t0 = c0; t0 < c0+cl; t0 += 4){
    float gl[4], gh[4], sum2[4];
    #pragma unroll
    for (int i=0;i<4;i++){
      const bf16* rr = xr + (long)(t0+i)*CONVD;
      unsigned xv = *(const unsigned*)(rr + xoff);
      short8 B0 = *(const short8*)(rr + DI);
      short8 B1 = *(const short8*)(rr + DI + 8);
      short8 C0 = *(const short8*)(rr + DI + DS);
      short8 C1 = *(const short8*)(rr + DI + DS + 8);
      unsigned zv = *(const unsigned*)(zrow + (long)(t0+i)*DPROJ + xoff);
      float2 dd = ddr[t0+i];
      float da = dd.x, dt = dd.y;
      float x0 = u32_lo(xv), x1 = u32_hi(xv);
      float xd0 = x0*dt, xd1 = x1*dt;
      float a0 = 0.f, a1 = 0.f;
      #pragma unroll
      for (int n=0;n<8;n++){
        float bb0 = b2f_raw(B0[n]), cc0 = b2f_raw(C0[n]);
        s0[n] = fmaf(da, s0[n], xd0*bb0);
        s1[n] = fmaf(da, s1[n], xd1*bb0);
        a0 = fmaf(s0[n], cc0, a0);
        a1 = fmaf(s1[n], cc0, a1);
        float bb1 = b2f_raw(B1[n]), cc1 = b2f_raw(C1[n]);
        s0[8+n] = fmaf(da, s0[8+n], xd0*bb1);
        s1[8+n] = fmaf(da, s1[8+n], xd1*bb1);
        a0 = fmaf(s0[8+n], cc1, a0);
        a1 = fmaf(s1[8+n], cc1, a1);
      }
      float y0 = a0 + Dv*x0, y1 = a1 + Dv*x1;
      float z0 = u32_lo(zv), z1 = u32_hi(zv);
      float g0 = y0 * z0 * (1.f/(1.f+expf(-z0)));
      float g1 = y1 * z1 * (1.f/(1.f+expf(-z1)));
      sum2[i] = g0*g0 + g1*g1;              // sum over UNSCALED g (pre-rw)
      gl[i] = g0*rwl; gh[i] = g1*rwh;       // store graw = g*rw
    }
    #pragma unroll
    for (int o=32;o;o>>=1){
      #pragma unroll
      for (int i=0;i<4;i++) sum2[i] += __shfl_down(sum2[i], o);
    }
    if (lane == 0){
      #pragma unroll
      for (int i=0;i<4;i++) psum[(rowB + t0 + i)*8 + h] = sum2[i];
    }
    #pragma unroll
    for (int i=0;i<4;i++)
      *(unsigned*)(zrow + (long)(t0+i)*DPROJ + xoff) = pack_bf16x2(gl[i], gh[i]);
  }
}

// scl[row] = rsqrt(mean(g^2) + eps) from 8 per-head partials
__global__ __launch_bounds__(256) void rms_scl(const float* __restrict__ psum,
                                               float* __restrict__ scl)
{
  int r = blockIdx.x*256 + threadIdx.x;     // 16384 rows
  float s = 0.f;
  #pragma unroll
  for (int w=0;w<8;w++) s += psum[(long)r*8 + w];
  scl[r] = rsqrtf(s*(1.f/DI) + 1e-5f);
}

// ---------------------------------------------------------------------------
// Final LN over concat(h_f[b,t], h_b[b,T-1-t]) (1024) -> d_out
// ---------------------------------------------------------------------------
__global__ __launch_bounds__(256) void final_ln(const bf16* __restrict__ h,
    const bf16* __restrict__ lw, const bf16* __restrict__ lb, void* out,
    int mode, const int* flagp)
{
  __shared__ float sb[8];
  int bt = blockIdx.x; int b = bt >> 11, t = bt & 2047;
  int f32out = mode ? *flagp : 0;
  const bf16* rf = h + (long)bt*DM;
  const bf16* rb = h + ((long)BT + (long)b*TT + (TT-1-t))*DM;
  float v[4], s = 0.f, ss = 0.f;
  #pragma unroll
  for (int i=0;i<4;i++){
    int c = threadIdx.x + i*256;
    v[i] = __bfloat162float(c < DM ? rf[c] : rb[c-DM]);
    s += v[i]; ss += v[i]*v[i];
  }
  red2(s, ss, sb);
  float m = s / (2*DM);
  float var = ss / (2*DM) - m*m;
  float rs = rsqrtf(fmaxf(var, 0.f) + 1e-5f);
  #pragma unroll
  for (int i=0;i<4;i++){
    int c = threadIdx.x + i*256;
    float o = (v[i]-m)*rs*__bfloat162float(lw[c]) + __bfloat162float(lb[c]);
    if (f32out) ((float*)out)[(long)bt*(2*DM) + c] = o;
    else        ((bf16*)out)[(long)bt*(2*DM) + c] = __float2bfloat16(o);
  }
}

// ---------------------------------------------------------------------------
extern "C" void kernel_launch(void* const* d_in, const int* in_sizes, int n_in,
                              void* d_out, int out_size, void* d_ws, size_t ws_size,
                              hipStream_t stream)
{
  char* wsp = (char*)d_ws;
  auto take = [&](size_t bytes){ char* p = wsp; wsp += (bytes + 63) & ~(size_t)63; return p; };
  int*   flagp = (int*)  take(4);
  bf16*  h     = (bf16*) take((size_t)2*BT*DM*2);      // 16.78 MB
  bf16*  zx    = (bf16*) take((size_t)2*BT*DPROJ*2);   // 68.42 MB (z gated in place)
  bf16*  xbc   = (bf16*) take((size_t)2*BT*CONVD*2);   // 34.60 MB
  float2* dadt = (float2*)take((size_t)2*BB*NH*TT*8);  // 1.05 MB
  float* draw  = (float*)take((size_t)2*BT*NH*4);      // 0.52 MB
  float* Pc    = (float*)take((size_t)64*64*4);        // 16 KB (max NCH=64)
  float* psum  = (float*)take((size_t)2*BT*8*4);       // 0.52 MB per-head g^2
  float* scl   = (float*)take((size_t)2*BT*4);         // 64 KB per-row scale
  char* preCanon = wsp;                                // direct-mode SC base

  static const int cnt[23] = {
    BT*256, DM*256, DM, DM, DM, 2*DM, 2*DM,
    NL*DPROJ*DM, NL*CONVD*4, NL*CONVD, NL*NH, NL*NH, NL*NH, NL*DI, NL*DM*DI,
    NL*DPROJ*DM, NL*CONVD*4, NL*CONVD, NL*NH, NL*NH, NL*NH, NL*DI, NL*DM*DI };
  bf16* canon[23];
  for (int i = 0; i < 23; ++i) canon[i] = (bf16*)take((size_t)cnt[i]*2);
  char* postCanon = wsp;

  // SC at workspace tail; chunk count picked to fit (16 == legacy config).
  const size_t scUnit = (size_t)NE*4;                  // 512 KB per chunk
  size_t usedFull   = (size_t)(postCanon - (char*)d_ws);
  size_t usedDirect = (size_t)(preCanon  - (char*)d_ws);
  int convMode, NCHR; float* SC;
  if      (ws_size >= usedFull + 64*scUnit){ convMode=1; NCHR=64; SC=(float*)postCanon; }
  else if (ws_size >= usedFull + 32*scUnit){ convMode=1; NCHR=32; SC=(float*)postCanon; }
  else if (ws_size >= usedFull + 16*scUnit){ convMode=1; NCHR=16; SC=(float*)postCanon; }
  else {
    convMode = 0;
    if      (ws_size >= usedDirect + 64*scUnit) NCHR=64;
    else if (ws_size >= usedDirect + 32*scUnit) NCHR=32;
    else                                        NCHR=16;
    SC = (float*)preCanon;                             // canon region unused
  }
  const int CLR = TT / NCHR;

  const bf16* in[23];
  if (convMode){
    detect_dtype<<<1,256,0,stream>>>(d_in[0], flagp);
    for (int i = 0; i < 23; ++i){
      int grid = (cnt[i] + 255)/256; if (grid > 2048) grid = 2048;
      convert_in<<<grid,256,0,stream>>>(d_in[i], canon[i], cnt[i], flagp);
      in[i] = canon[i];
    }
  } else {
    for (int i = 0; i < 23; ++i) in[i] = (const bf16*)d_in[i];
  }

  const bf16* x       = in[0];
  const bf16* embed_w = in[1];
  const bf16* embed_b = in[2];
  const bf16* ln1_w   = in[3];
  const bf16* ln1_b   = in[4];
  const bf16* lnout_w = in[5];
  const bf16* lnout_b = in[6];
  const bf16* in_w[2]   = {in[7],  in[15]};
  const bf16* conv_w[2] = {in[8],  in[16]};
  const bf16* conv_b[2] = {in[9],  in[17]};
  const bf16* dt_b[2]   = {in[10], in[18]};
  const bf16* A_log[2]  = {in[11], in[19]};
  const bf16* Dp[2]     = {in[12], in[20]};
  const bf16* rms_w[2]  = {in[13], in[21]};
  const bf16* out_w[2]  = {in[14], in[22]};

  bf16* hpre = xbc;   // embed output parks in xbc (free until layer-0 conv)

  gemm_nt<1><<<dim3(64,4,1),256,0,stream>>>(x, embed_w, embed_w, hpre, embed_b, nullptr,
                                            BT, DM, 256, 256, 0, 0);
  embed_ln<<<dim3(BT),256,0,stream>>>(hpre, ln1_w, ln1_b, h);

  for (int i = 0; i < NL; ++i){
    gemm_nt<3><<<dim3(64,17,2),256,0,stream>>>(h, in_w[0]+(size_t)i*DPROJ*DM, in_w[1]+(size_t)i*DPROJ*DM,
        zx, nullptr, draw, BT, DPROJ, DM, DM, (long)BT*DM, (long)BT*DPROJ);
    conv_silu<<<dim3(BT,2),256,0,stream>>>(zx, conv_w[0]+(size_t)i*CONVD*4, conv_w[1]+(size_t)i*CONVD*4,
        conv_b[0]+(size_t)i*CONVD, conv_b[1]+(size_t)i*CONVD, xbc);
    dt_kernel<<<dim3(512),256,0,stream>>>(draw, dt_b[0]+i*NH, dt_b[1]+i*NH,
        A_log[0]+i*NH, A_log[1]+i*NH, dadt);
    chunk_local<<<dim3(NCHR,16),256,0,stream>>>(xbc, dadt, SC, Pc, CLR, NCHR);
    if      (NCHR == 64) chunk_combine<64><<<dim3(NE/256),256,0,stream>>>(SC, Pc);
    else if (NCHR == 32) chunk_combine<32><<<dim3(NE/256),256,0,stream>>>(SC, Pc);
    else                 chunk_combine<16><<<dim3(NE/256),256,0,stream>>>(SC, Pc);
    chunk_apply_gate<<<dim3(NCHR,8),512,0,stream>>>(xbc, zx, dadt, SC,
        Dp[0]+i*NH, Dp[1]+i*NH, rms_w[0]+(size_t)i*DI, rms_w[1]+(size_t)i*DI, psum, CLR);
    rms_scl<<<dim3(2*BT/256),256,0,stream>>>(psum, scl);
    gemm_nt<4><<<dim3(64,4,2),256,0,stream>>>(zx, out_w[0]+(size_t)i*DM*DI, out_w[1]+(size_t)i*DM*DI,
        h, h, scl, BT, DM, DI, DPROJ, (long)BT*DPROJ, (long)BT*DM);
  }

  final_ln<<<dim3(BT),256,0,stream>>>(h, lnout_w, lnout_b, d_out, convMode, flagp);
  (void)in_sizes; (void)n_in; (void)out_size;
}